// Round 1
// baseline (1716.089 us; speedup 1.0000x reference)
//
#include <hip/hip_runtime.h>

typedef __bf16 bf16x8 __attribute__((ext_vector_type(8)));
typedef float f32x4 __attribute__((ext_vector_type(4)));
typedef unsigned short u16;
typedef unsigned int u32;

#define WIN_N 49
#define CDIM 384
#define NHEADS 12
#define HDIM 32
#define SCALE 0.17677669529663687f

__device__ __forceinline__ u16 f2bf(float f) {
  u32 u = __float_as_uint(f);
  u32 r = (u + 0x7FFFu + ((u >> 16) & 1u)) >> 16;
  return (u16)r;
}

// MFMA fragment load from an LDS matrix stored row-major (stride in u16 elems,
// stride % 8 == 0 so each 16B read is aligned). Returns zero for rows >= nrows.
// Layout per verified gfx950 mapping: elem j of lane = M[row][k0 + quad*8 + j].
__device__ __forceinline__ bf16x8 ld_frag(const u16* base, int row, int nrows,
                                          int stride, int k0, int quad) {
  bf16x8 z = {};
  if (row < nrows)
    z = *(const bf16x8*)(base + row * stride + k0 + quad * 8);
  return z;
}

// ---------------- prep: weights -> bf16, bias table gather ----------------
__global__ void prep_kernel(const float* __restrict__ qkv_w,
                            const float* __restrict__ proj_w,
                            const float* __restrict__ bias_table,
                            const int* __restrict__ rel_index,
                            u16* __restrict__ qkvWb, u16* __restrict__ projWb,
                            float* __restrict__ biasF) {
  int i = blockIdx.x * blockDim.x + threadIdx.x;
  int stride = gridDim.x * blockDim.x;
  for (int t = i; t < 3 * CDIM * CDIM; t += stride) qkvWb[t] = f2bf(qkv_w[t]);
  for (int t = i; t < CDIM * CDIM; t += stride) projWb[t] = f2bf(proj_w[t]);
  for (int t = i; t < NHEADS * WIN_N * WIN_N; t += stride) {
    int h = t / (WIN_N * WIN_N);
    int r = t - h * (WIN_N * WIN_N);
    biasF[t] = bias_table[rel_index[r] * NHEADS + h];
  }
}

// ---------------- fused window attention ----------------
// 1 block = 1 window. 256 threads = 4 waves.
// Head-group loop (2 heads/group, 6 groups):
//   QKV (MFMA, X from LDS, W from global bf16) -> Q,K (LDS [tok][64]) / V (LDS [d][tok])
//   S = Q@K^T (MFMA) -> quad-shuffle softmax -> P (LDS, aliases Q/K)
//   O = P@V (MFMA) -> Og (LDS [tok][64])
//   proj: pacc += Og @ projW[:, g*64:+64]^T  (acc held in registers across groups)
__global__ void __launch_bounds__(256, 2)
swin_fused(const float* __restrict__ x, const float* __restrict__ qkv_b,
           const float* __restrict__ proj_b, const u16* __restrict__ qkvWb,
           const u16* __restrict__ projWb, const float* __restrict__ biasF,
           float* __restrict__ out) {
  // LDS map (u16 elems):
  //  Xb  @ 0      : 49 x 392  = 19208   (stride 392: 784B rows, 16B aligned)
  //  Qb  @ 19208  : 49 x 72   = 3528    (cols: head0 d0..31 | head1 d0..31)
  //  Kb  @ 22736  : 49 x 72   = 3528
  //  Pb  @ 19208  : 2 x 49x72           (aliases Qb+Kb after barrier (c))
  //  Vt  @ 26264  : 64 x 72   = 4608    (row = group-local feature, col = token)
  //  Og  @ 30872  : 49 x 72   = 3528
  __shared__ __align__(16) u16 sm[34400];  // 68,800 B -> 2 blocks/CU
  u16* Xb = sm;
  u16* Qb = sm + 19208;
  u16* Kb = sm + 22736;
  u16* Pb = sm + 19208;
  u16* Vt = sm + 26264;
  u16* Og = sm + 30872;

  const int tid = threadIdx.x;
  const int w = tid >> 6, lane = tid & 63, quad = lane >> 4, l16 = lane & 15;
  const int b = blockIdx.x;
  const int mhalf = w & 1, hh = w >> 1;  // attention: wave -> (head hh, M-half)

  // ---- stage X -> LDS bf16 ----
  const float4* xs = (const float4*)(x + (size_t)b * (WIN_N * CDIM));
  for (int i = tid; i < WIN_N * (CDIM / 4); i += 256) {
    int m = i / 96, c4 = (i - m * 96) * 4;
    float4 v = xs[i];
    u32* dst = (u32*)(Xb + m * 392 + c4);
    dst[0] = (u32)f2bf(v.x) | ((u32)f2bf(v.y) << 16);
    dst[1] = (u32)f2bf(v.z) | ((u32)f2bf(v.w) << 16);
  }
  // zero Vt once (token cols 49..71 must stay 0 across all groups)
  for (int i = tid; i < (64 * 72) / 2; i += 256) ((u32*)Vt)[i] = 0u;

  f32x4 pacc[6][4];  // proj accumulators: 6 N-tiles (wave's 96 cols) x 4 M-tiles
#pragma unroll
  for (int t = 0; t < 6; ++t)
#pragma unroll
    for (int mt = 0; mt < 4; ++mt) pacc[t][mt] = (f32x4){0.f, 0.f, 0.f, 0.f};

  for (int g = 0; g < 6; ++g) {
    __syncthreads();  // (a) Xb/Vt ready; prior group done with Pb/Vt/Og reads

    // ---- QKV: 12 col-tiles (Qh0 Qh1 Kh0 Kh1 Vh0 Vh1 x 2 halves), 3/wave ----
    int mat[3], hhc[3], half[3], orow[3];
#pragma unroll
    for (int tl = 0; tl < 3; ++tl) {
      int t = w * 3 + tl;
      int chunk = t >> 1;       // 0..5
      half[tl] = t & 1;         // which 16-col half of the 32
      mat[tl] = chunk >> 1;     // 0=Q 1=K 2=V
      hhc[tl] = chunk & 1;      // head within group
      orow[tl] = mat[tl] * CDIM + (g * 2 + hhc[tl]) * HDIM + half[tl] * 16 + l16;
    }
    f32x4 acc[3][4];
#pragma unroll
    for (int tl = 0; tl < 3; ++tl)
#pragma unroll
      for (int mt = 0; mt < 4; ++mt) acc[tl][mt] = (f32x4){0.f, 0.f, 0.f, 0.f};

    for (int k = 0; k < 12; ++k) {  // K = 384 = 12 x 32
      bf16x8 a[4];
#pragma unroll
      for (int mt = 0; mt < 4; ++mt)
        a[mt] = ld_frag(Xb, mt * 16 + l16, WIN_N, 392, k * 32, quad);
#pragma unroll
      for (int tl = 0; tl < 3; ++tl) {
        bf16x8 bw = *(const bf16x8*)(qkvWb + (size_t)orow[tl] * CDIM + k * 32 + quad * 8);
#pragma unroll
        for (int mt = 0; mt < 4; ++mt)
          acc[tl][mt] = __builtin_amdgcn_mfma_f32_16x16x32_bf16(a[mt], bw, acc[tl][mt], 0, 0, 0);
      }
    }
#pragma unroll
    for (int tl = 0; tl < 3; ++tl) {
      float bias = qkv_b[orow[tl]];
      int col = hhc[tl] * HDIM + half[tl] * 16 + l16;
#pragma unroll
      for (int mt = 0; mt < 4; ++mt)
#pragma unroll
        for (int r = 0; r < 4; ++r) {
          int tok = mt * 16 + quad * 4 + r;  // C/D row = quad*4 + reg
          if (tok < WIN_N) {
            u16 hv = f2bf(acc[tl][mt][r] + bias);
            if (mat[tl] == 0)      Qb[tok * 72 + col] = hv;
            else if (mat[tl] == 1) Kb[tok * 72 + col] = hv;
            else                   Vt[col * 72 + tok] = hv;  // transposed
          }
        }
    }
    __syncthreads();  // (b) Q,K,V ready

    // ---- S = Q @ K^T (per wave: head hh, M-tiles {2*mhalf, 2*mhalf+1}) ----
    f32x4 S[2][4];
    bf16x8 aq[2];
#pragma unroll
    for (int mt2 = 0; mt2 < 2; ++mt2)
      aq[mt2] = ld_frag(Qb, (2 * mhalf + mt2) * 16 + l16, WIN_N, 72, hh * HDIM, quad);
#pragma unroll
    for (int nt = 0; nt < 4; ++nt) {
      bf16x8 bk = ld_frag(Kb, nt * 16 + l16, WIN_N, 72, hh * HDIM, quad);
#pragma unroll
      for (int mt2 = 0; mt2 < 2; ++mt2) {
        f32x4 z = (f32x4){0.f, 0.f, 0.f, 0.f};
        S[mt2][nt] = __builtin_amdgcn_mfma_f32_16x16x32_bf16(aq[mt2], bk, z, 0, 0, 0);
      }
    }
    // ---- softmax over rows (row lives in one 16-lane quad group) ----
    const int hglob = g * 2 + hh;
#pragma unroll
    for (int mt2 = 0; mt2 < 2; ++mt2)
#pragma unroll
      for (int r = 0; r < 4; ++r) {
        int m = (2 * mhalf + mt2) * 16 + quad * 4 + r;
        float v[4];
#pragma unroll
        for (int nt = 0; nt < 4; ++nt) {
          int n = nt * 16 + l16;
          float s;
          if (m < WIN_N && n < WIN_N)
            s = S[mt2][nt][r] * SCALE + biasF[(hglob * WIN_N + m) * WIN_N + n];
          else
            s = (m >= WIN_N) ? 0.f : -1e30f;  // pad rows: benign; pad cols: -inf
          v[nt] = s;
        }
        float mx = fmaxf(fmaxf(v[0], v[1]), fmaxf(v[2], v[3]));
        mx = fmaxf(mx, __shfl_xor(mx, 1));
        mx = fmaxf(mx, __shfl_xor(mx, 2));
        mx = fmaxf(mx, __shfl_xor(mx, 4));
        mx = fmaxf(mx, __shfl_xor(mx, 8));
        float sum = 0.f;
#pragma unroll
        for (int nt = 0; nt < 4; ++nt) {
          v[nt] = __expf(v[nt] - mx);
          sum += v[nt];
        }
        sum += __shfl_xor(sum, 1);
        sum += __shfl_xor(sum, 2);
        sum += __shfl_xor(sum, 4);
        sum += __shfl_xor(sum, 8);
        float inv = 1.f / sum;
#pragma unroll
        for (int nt = 0; nt < 4; ++nt) S[mt2][nt][r] = v[nt] * inv;
      }
    __syncthreads();  // (c) all waves done reading Qb/Kb -> safe to alias with P

    // ---- write P (bf16) into Qb/Kb region; cols 49..63 are exact zeros ----
    u16* Ph = Pb + hh * 3528;
#pragma unroll
    for (int mt2 = 0; mt2 < 2; ++mt2)
#pragma unroll
      for (int nt = 0; nt < 4; ++nt)
#pragma unroll
        for (int r = 0; r < 4; ++r) {
          int m = (2 * mhalf + mt2) * 16 + quad * 4 + r;
          if (m < WIN_N) Ph[m * 72 + nt * 16 + l16] = f2bf(S[mt2][nt][r]);
        }
    __syncthreads();  // (d)

    // ---- O = P @ V ----
    f32x4 o2[2][2];
#pragma unroll
    for (int mt2 = 0; mt2 < 2; ++mt2)
#pragma unroll
      for (int nt2 = 0; nt2 < 2; ++nt2) o2[mt2][nt2] = (f32x4){0.f, 0.f, 0.f, 0.f};
    bf16x8 bv[2][2];
#pragma unroll
    for (int nt2 = 0; nt2 < 2; ++nt2)
#pragma unroll
      for (int kk = 0; kk < 2; ++kk)
        bv[nt2][kk] = ld_frag(Vt, hh * HDIM + nt2 * 16 + l16, 64, 72, kk * 32, quad);
#pragma unroll
    for (int mt2 = 0; mt2 < 2; ++mt2)
#pragma unroll
      for (int kk = 0; kk < 2; ++kk) {
        bf16x8 ap = ld_frag(Ph, (2 * mhalf + mt2) * 16 + l16, WIN_N, 72, kk * 32, quad);
#pragma unroll
        for (int nt2 = 0; nt2 < 2; ++nt2)
          o2[mt2][nt2] = __builtin_amdgcn_mfma_f32_16x16x32_bf16(ap, bv[nt2][kk], o2[mt2][nt2], 0, 0, 0);
      }
    // ---- write Og (bf16, cols = group-local feature) ----
#pragma unroll
    for (int mt2 = 0; mt2 < 2; ++mt2)
#pragma unroll
      for (int nt2 = 0; nt2 < 2; ++nt2)
#pragma unroll
        for (int r = 0; r < 4; ++r) {
          int tok = (2 * mhalf + mt2) * 16 + quad * 4 + r;
          if (tok < WIN_N)
            Og[tok * 72 + hh * HDIM + nt2 * 16 + l16] = f2bf(o2[mt2][nt2][r]);
        }
    __syncthreads();  // (f) Og ready

    // ---- proj accumulate: pacc += Og @ projW[:, g*64 : g*64+64]^T ----
#pragma unroll
    for (int kk = 0; kk < 2; ++kk) {
      bf16x8 ao[4];
#pragma unroll
      for (int mt = 0; mt < 4; ++mt)
        ao[mt] = ld_frag(Og, mt * 16 + l16, WIN_N, 72, kk * 32, quad);
#pragma unroll
      for (int t6 = 0; t6 < 6; ++t6) {
        int nrow = w * 96 + t6 * 16 + l16;
        bf16x8 bw = *(const bf16x8*)(projWb + (size_t)nrow * CDIM + g * 64 + kk * 32 + quad * 8);
#pragma unroll
        for (int mt = 0; mt < 4; ++mt)
          pacc[t6][mt] = __builtin_amdgcn_mfma_f32_16x16x32_bf16(ao[mt], bw, pacc[t6][mt], 0, 0, 0);
      }
    }
  }

  // ---- epilogue ----
  float* outp = out + (size_t)b * (WIN_N * CDIM);
#pragma unroll
  for (int t6 = 0; t6 < 6; ++t6) {
    int n = w * 96 + t6 * 16 + l16;
    float pb = proj_b[n];
#pragma unroll
    for (int mt = 0; mt < 4; ++mt)
#pragma unroll
      for (int r = 0; r < 4; ++r) {
        int m = mt * 16 + quad * 4 + r;
        if (m < WIN_N) outp[m * CDIM + n] = pacc[t6][mt][r] + pb;
      }
  }
}

extern "C" void kernel_launch(void* const* d_in, const int* in_sizes, int n_in,
                              void* d_out, int out_size, void* d_ws, size_t ws_size,
                              hipStream_t stream) {
  const float* x          = (const float*)d_in[0];
  const float* qkv_w      = (const float*)d_in[1];
  const float* qkv_b      = (const float*)d_in[2];
  const float* proj_w     = (const float*)d_in[3];
  const float* proj_b     = (const float*)d_in[4];
  const float* bias_table = (const float*)d_in[5];
  const int*   rel_index  = (const int*)d_in[6];

  // ws layout: qkv_w bf16 (884,736 B) | proj_w bf16 (294,912 B) | biasF fp32 (115,248 B)
  u16* qkvWb = (u16*)d_ws;
  u16* projWb = qkvWb + 3 * CDIM * CDIM;
  float* biasF = (float*)(projWb + CDIM * CDIM);

  hipLaunchKernelGGL(prep_kernel, dim3(512), dim3(256), 0, stream,
                     qkv_w, proj_w, bias_table, rel_index, qkvWb, projWb, biasF);
  hipLaunchKernelGGL(swin_fused, dim3(4096), dim3(256), 0, stream,
                     x, qkv_b, proj_b, qkvWb, projWb, biasF, (float*)d_out);
}